// Round 11
// baseline (137.048 us; speedup 1.0000x reference)
//
#include <hip/hip_runtime.h>

// SparseNeuralNetwork: 256 independent sub-nets j = i*16 + o (i,o in [0,16)).
//   layer0: v[k] = relu(W0[16j+k, i] * x[b,i] + b0[16j+k]),   k in [0,16)
//   layer1: u[m] = relu(b1[8j+m] + sum_k W1[8j+m, 16j+k] * v[k]), m in [0,8)
//   out[b,o] = b2[o] + sum_i sum_m W2[o, 8j+m] * u[m]
//
// R11 = R10 staging/layout + two throughput changes:
//  (a) v2f batch-pair compute -> v_pk_fma_f32 (half the VALU instructions)
//  (b) 4-elem packed butterfly: reduce bit0 (4 shfl), cndmask-pack pairs into
//      bit0, reduce bit2 (2 shfl), pack into bit2, reduce bits3-5 (3 shfl)
//      = 9 shfl / 4 elems (was 5/elem); shorter dependent chains, 8 lanes store.
// Lane = i*4 + o2*2 + h (half-split, 104 weight VGPRs); live ~185 < 256 cap.
// Grid 8 og x 64 chunks = 512 blocks x 4 waves = 2 waves/SIMD.

#define BATCH   8192
#define IN_DIM  16
#define OUT_DIM 16
#define H0      16
#define H1      8
#define D0      (IN_DIM * OUT_DIM * H0)   // 4096
#define D1      (IN_DIM * OUT_DIM * H1)   // 2048
#define NR4 26

typedef float v2f __attribute__((ext_vector_type(2)));

__global__ __launch_bounds__(256, 2) void mlp_fused(
    const float* __restrict__ x,
    const float* __restrict__ W0, const float* __restrict__ b0,
    const float* __restrict__ W1, const float* __restrict__ b1,
    const float* __restrict__ W2, const float* __restrict__ b2,
    float* __restrict__ out)
{
    __shared__ float4 sW[NR4][64];        // 26,624 B, transposed per-lane

    const int tid = threadIdx.x;
    const int og  = blockIdx.y;           // o-pair: o = og*2 + o2
    const int bb  = blockIdx.x * 128;     // 128 batch elems per block

    // ---- cooperative stage: slot s (0..63): h=s&1, o2=(s>>1)&1, i=s>>2 ----
    for (int idx = tid; idx < NR4 * 64; idx += 256) {
        const int s  = idx & 63, r4 = idx >> 6;
        const int h  = s & 1, o2 = (s >> 1) & 1, i = s >> 2;
        const int o  = og * 2 + o2;
        const int j  = i * 16 + o;
        float4 val;
        if (r4 < 4) {                      // w0: col-i gather (4 scalar)
            val.x = W0[(j * H0 + 4*r4    ) * IN_DIM + i];
            val.y = W0[(j * H0 + 4*r4 + 1) * IN_DIM + i];
            val.z = W0[(j * H0 + 4*r4 + 2) * IN_DIM + i];
            val.w = W0[(j * H0 + 4*r4 + 3) * IN_DIM + i];
        } else if (r4 < 8) {               // b0: aligned float4
            val = *(const float4*)(b0 + j * H0 + (r4 - 4) * 4);
        } else if (r4 < 24) {              // w1: row h*4+mm, quarter kq
            const int rr = r4 - 8, mm = rr >> 2, kq = rr & 3;
            val = *(const float4*)(W1 + (size_t)(j * H1 + h * 4 + mm) * D0
                                      + j * H0 + kq * 4);
        } else if (r4 == 24) {             // b1 quarter
            val = *(const float4*)(b1 + j * H1 + h * 4);
        } else {                           // w2 quarter
            val = *(const float4*)(W2 + o * D1 + j * H1 + h * 4);
        }
        sW[r4][s] = val;
    }
    __syncthreads();

    // ---- one-time: lane's 104 weights -> VGPRs (26 conflict-free b128) ----
    const int l  = tid & 63;
    const int wv = tid >> 6;
    float w[104];
    #pragma unroll
    for (int r4 = 0; r4 < NR4; ++r4) {
        const float4 q = sW[r4][l];
        w[4*r4] = q.x; w[4*r4+1] = q.y; w[4*r4+2] = q.z; w[4*r4+3] = q.w;
    }

    const int o2 = (l >> 1) & 1;
    const int i  = l >> 2;
    const int o  = og * 2 + o2;
    const int bbw = bb + wv * 32;          // this wave's 32 batch elems

    // ---- x preload: lane's column i, batch pairs as v2f ----
    v2f xi[16];
    {
        const float* __restrict__ xp = x + (size_t)bbw * IN_DIM + i;
        #pragma unroll
        for (int t = 0; t < 16; ++t)
            xi[t] = (v2f){xp[(2*t) * IN_DIM], xp[(2*t+1) * IN_DIM]};
    }

    const float b2v = b2[o];

    // ---- register-resident compute: 8 groups of 4 batch elems ----
    #pragma unroll
    for (int g = 0; g < 8; ++g) {
        v2f acc01, acc23;
        {
            const v2f xv = xi[2*g];
            v2f v[H0];
            #pragma unroll
            for (int k = 0; k < H0; ++k)
                v[k] = __builtin_elementwise_max(w[k] * xv + w[16 + k], (v2f)0.0f);
            v2f acc = (v2f)0.0f;
            #pragma unroll
            for (int mm = 0; mm < 4; ++mm) {
                v2f u = (v2f)(w[96 + mm]);
                #pragma unroll
                for (int k = 0; k < H0; ++k)
                    u += w[32 + mm * 16 + k] * v[k];
                acc += w[100 + mm] * __builtin_elementwise_max(u, (v2f)0.0f);
            }
            acc01 = acc;
        }
        {
            const v2f xv = xi[2*g + 1];
            v2f v[H0];
            #pragma unroll
            for (int k = 0; k < H0; ++k)
                v[k] = __builtin_elementwise_max(w[k] * xv + w[16 + k], (v2f)0.0f);
            v2f acc = (v2f)0.0f;
            #pragma unroll
            for (int mm = 0; mm < 4; ++mm) {
                v2f u = (v2f)(w[96 + mm]);
                #pragma unroll
                for (int k = 0; k < H0; ++k)
                    u += w[32 + mm * 16 + k] * v[k];
                acc += w[100 + mm] * __builtin_elementwise_max(u, (v2f)0.0f);
            }
            acc23 = acc;
        }

        // packed butterfly: 9 shfl for 4 batch elems
        float a0 = acc01.x, a1 = acc01.y, a2 = acc23.x, a3 = acc23.y;
        a0 += __shfl_xor(a0, 1, 64);
        a1 += __shfl_xor(a1, 1, 64);
        a2 += __shfl_xor(a2, 1, 64);
        a3 += __shfl_xor(a3, 1, 64);
        float p = (l & 1) ? a1 : a0;       // bit0 now encodes elem parity
        float q = (l & 1) ? a3 : a2;
        p += __shfl_xor(p, 4, 64);
        q += __shfl_xor(q, 4, 64);
        float r = (l & 4) ? q : p;         // bit2 now encodes elem pair
        r += __shfl_xor(r, 8, 64);
        r += __shfl_xor(r, 16, 64);
        r += __shfl_xor(r, 32, 64);
        if (l < 8) {
            const int delta = (l & 1) + ((l >> 1) & 2);   // bit0 + 2*bit2
            out[(size_t)(bbw + 4*g + delta) * OUT_DIM + o] = r + b2v;
        }
    }
}

extern "C" void kernel_launch(void* const* d_in, const int* in_sizes, int n_in,
                              void* d_out, int out_size, void* d_ws, size_t ws_size,
                              hipStream_t stream) {
    const float* x  = (const float*)d_in[0];
    const float* W0 = (const float*)d_in[1];
    const float* b0 = (const float*)d_in[2];
    const float* W1 = (const float*)d_in[3];
    const float* b1 = (const float*)d_in[4];
    const float* W2 = (const float*)d_in[5];
    const float* b2 = (const float*)d_in[6];
    float* out = (float*)d_out;

    dim3 grid(BATCH / 128, 8);            // 64 chunks x 8 o-pairs = 512 blocks
    mlp_fused<<<grid, 256, 0, stream>>>(x, W0, b0, W1, b1, W2, b2, out);
}

// Round 12
// 101.061 us; speedup vs baseline: 1.3561x; 1.3561x over previous
//
#include <hip/hip_runtime.h>

// SparseNeuralNetwork: 256 independent sub-nets j = i*16 + o (i,o in [0,16)).
//   layer0: v[k] = relu(W0[16j+k, i] * x[b,i] + b0[16j+k]),   k in [0,16)
//   layer1: u[m] = relu(b1[8j+m] + sum_k W1[8j+m, 16j+k] * v[k]), m in [0,8)
//   out[b,o] = b2[o] + sum_i sum_m W2[o, 8j+m] * u[m]
//
// R12: the session's recurring killer is VGPR spill: allocator caps at 128
// for these kernels (R8/R11 counters: VGPR=128 + 60-270MB scratch traffic).
// Fix: 4-lane sub-net split (lane = i*4 + h; h owns W1 rows 2h,2h+1) ->
// 68 weight VGPRs, live ~112 < 128. No spill AND 4 waves/SIMD
// (__launch_bounds__(256,4)). Weights via R7-style coalesced packT (17
// float4/lane); 32 batch/wave in two xi[16] halves; i+h reduction =
// pair-packed shfl_xor butterfly (8 shfl / 2 elems, lanes 0,1 store).
// Grid 16 o x 256 chunks = 4096 waves = 1024 blocks = 4 blocks/CU.

#define BATCH   8192
#define IN_DIM  16
#define OUT_DIM 16
#define H0      16
#define H1      8
#define D0      (IN_DIM * OUT_DIM * H0)   // 4096
#define D1      (IN_DIM * OUT_DIM * H1)   // 2048
#define NRL     68                         // per-lane weights (17 float4)
#define NSLOT   1024                       // 16 o x 64 lanes

// packT: float4 row r4 (0..16) of slot s at packT4[r4*1024 + s]
// slot s: l = s&63, o = s>>6; i = l>>2, h = l&3, j = i*16+o
// per-lane floats r: [0..15] w0 | [16..31] b0 | [32..63] w1 rows 2h,2h+1 |
//                    [64..65] b1[8j+2h..] | [66..67] w2[o*2048+8j+2h..]
__global__ void prep_kernel(const float* __restrict__ W0, const float* __restrict__ b0,
                            const float* __restrict__ W1, const float* __restrict__ b1,
                            const float* __restrict__ W2, float* __restrict__ packT)
{
    const int t = blockIdx.x * 256 + threadIdx.x;   // 0..69631
    const int c = t & 3;
    const int q = t >> 2;
    const int s = q & (NSLOT - 1);
    const int r4 = q >> 10;
    const int r = r4 * 4 + c;
    const int l = s & 63, o = s >> 6;
    const int i = l >> 2, h = l & 3;
    const int j = i * 16 + o;
    float val;
    if      (r < 16)  val = W0[(j * H0 + r) * IN_DIM + i];
    else if (r < 32)  val = b0[j * H0 + (r - 16)];
    else if (r < 64)  { const int rr = r - 32, m = h * 2 + (rr >> 4), k = rr & 15;
                        val = W1[(size_t)(j * H1 + m) * D0 + j * H0 + k]; }
    else if (r < 66)  val = b1[j * H1 + h * 2 + (r - 64)];
    else              val = W2[o * D1 + j * H1 + h * 2 + (r - 66)];
    packT[t] = val;                                  // coalesced write
}

__global__ __launch_bounds__(256, 4) void mlp_main(
    const float* __restrict__ packT,
    const float* __restrict__ x,
    const float* __restrict__ b2,
    float* __restrict__ out)
{
    const int tid = threadIdx.x;
    const int l   = tid & 63;
    const int wv  = __builtin_amdgcn_readfirstlane(tid >> 6);
    const int wid = blockIdx.x * 4 + wv;
    const int o   = wid & 15;               // wave-uniform
    const int bb  = (wid >> 4) * 32;        // 32 batch elems per wave
    const int i   = l >> 2;

    // ---- one-time: lane's 68 weights via 17 coalesced float4 loads ----
    float w[NRL];
    {
        const float4* __restrict__ p4 = (const float4*)packT + o * 64 + l;
        #pragma unroll
        for (int r4 = 0; r4 < 17; ++r4) {
            const float4 q = p4[(size_t)r4 * NSLOT];
            w[4*r4] = q.x; w[4*r4+1] = q.y; w[4*r4+2] = q.z; w[4*r4+3] = q.w;
        }
    }
    const float b2v = b2[o];

    #pragma unroll
    for (int half = 0; half < 2; ++half) {
        const int bh = bb + half * 16;

        // x preload: lane's column i for 16 batch elems
        float xi[16];
        {
            const float* __restrict__ xp = x + (size_t)bh * IN_DIM + i;
            #pragma unroll
            for (int t = 0; t < 16; ++t) xi[t] = xp[t * IN_DIM];
        }

        // 8 groups of 2 batch elems
        #pragma unroll
        for (int g = 0; g < 8; ++g) {
            float a, b;
            #pragma unroll
            for (int e = 0; e < 2; ++e) {
                const float xv = xi[2*g + e];
                float v[H0];
                #pragma unroll
                for (int k = 0; k < H0; ++k)
                    v[k] = fmaxf(fmaf(w[k], xv, w[16 + k]), 0.0f);
                float acc = 0.0f;
                #pragma unroll
                for (int row = 0; row < 2; ++row) {
                    float u = w[64 + row];
                    #pragma unroll
                    for (int k = 0; k < H0; ++k)
                        u = fmaf(w[32 + row * 16 + k], v[k], u);
                    acc = fmaf(w[66 + row], fmaxf(u, 0.0f), acc);
                }
                if (e == 0) a = acc; else b = acc;
            }

            // pair-packed butterfly: reduce h (bits 0-1) for both, pack by
            // bit0, reduce i (bits 2-5). Lanes 0,1 hold elems 2g, 2g+1.
            a += __shfl_xor(a, 1, 64);  a += __shfl_xor(a, 2, 64);
            b += __shfl_xor(b, 1, 64);  b += __shfl_xor(b, 2, 64);
            float p = (l & 1) ? b : a;
            p += __shfl_xor(p, 4, 64);
            p += __shfl_xor(p, 8, 64);
            p += __shfl_xor(p, 16, 64);
            p += __shfl_xor(p, 32, 64);
            if (l < 2)
                out[(size_t)(bh + 2*g + l) * OUT_DIM + o] = p + b2v;
        }
    }
}

extern "C" void kernel_launch(void* const* d_in, const int* in_sizes, int n_in,
                              void* d_out, int out_size, void* d_ws, size_t ws_size,
                              hipStream_t stream) {
    const float* x  = (const float*)d_in[0];
    const float* W0 = (const float*)d_in[1];
    const float* b0 = (const float*)d_in[2];
    const float* W1 = (const float*)d_in[3];
    const float* b1 = (const float*)d_in[4];
    const float* W2 = (const float*)d_in[5];
    const float* b2 = (const float*)d_in[6];
    float* out   = (float*)d_out;
    float* packT = (float*)d_ws;            // 68*1024*4 = 278,528 B

    prep_kernel<<<272, 256, 0, stream>>>(W0, b0, W1, b1, W2, packT);

    // 4096 waves: wid = blk*4+wv; o = wid&15, chunk = wid>>4 (32 elems each)
    mlp_main<<<1024, 256, 0, stream>>>(packT, x, b2, out);
}